// Round 5
// baseline (41460.199 us; speedup 1.0000x reference)
//
#include <hip/hip_runtime.h>
#include <hip/hip_bf16.h>
#include <stdint.h>

#define B_  128
#define T_  512
#define H_  1024
#define E_  1024
#define NC_ 10
#define NT_ (B_*T_)   // 65536

typedef __attribute__((ext_vector_type(8))) short  short8;
typedef __attribute__((ext_vector_type(4))) float  f32x4;

static __device__ __forceinline__ float bf2f(ushort u){
  union { uint u; float f; } v; v.u = ((uint)u) << 16; return v.f;
}
static __device__ __forceinline__ ushort f2bf(float f){
  union { float f; uint u; } v; v.f = f;
  uint u = v.u;
  uint lsb = (u >> 16) & 1u;
  u += 0x7fffu + lsb;          // round-to-nearest-even
  return (ushort)(u >> 16);
}
static __device__ __forceinline__ float fsig(float x){ return 1.f / (1.f + __expf(-x)); }
static __device__ __forceinline__ float ftanh(float x){
  float e = __expf(2.f * x);
  return 1.f - 2.f / (e + 1.f);
}

// async global->LDS, 16B per lane. LDS dst wave-uniform; HW adds lane*16. Global src per-lane.
#define ASYNC_COPY16(gsrc, ldsdst) \
  __builtin_amdgcn_global_load_lds((const __attribute__((address_space(1))) uint32_t*)(gsrc), \
                                   (__attribute__((address_space(3))) uint32_t*)(ldsdst), 16, 0, 0)

// L2-coherent poll load: sc0 bypasses L1, reads this XCD's L2.
static __device__ __forceinline__ uint poll_sc0(const uint* p){
  uint v;
  asm volatile("global_load_dword %0, %1, off sc0\n\t"
               "s_waitcnt vmcnt(0)"
               : "=v"(v) : "v"(p) : "memory");
  return v;
}
static __device__ __forceinline__ long long rtclock(){
  return (long long)__builtin_amdgcn_s_memrealtime();
}

// ---------------- alive[t] = cumprod(colsum(x) != 0) ----------------
__global__ __launch_bounds__(512) void k_alive(const int* __restrict__ x,
                                               float* __restrict__ alive,
                                               float* __restrict__ aliveSum){
  __shared__ float fl[T_];
  int t = threadIdx.x;
  int s = 0;
  for (int b = 0; b < B_; ++b) s += x[b*T_ + t];
  fl[t] = (s != 0) ? 1.f : 0.f;
  __syncthreads();
  if (t == 0){
    float run = 1.f, sum = 0.f;
    for (int i = 0; i < T_; ++i){ run *= fl[i]; alive[i] = run; sum += run; }
    aliveSum[0] = sum;
  }
}

// ---------------- weight conversion: Wc -> bf16 (stride 2048) ----------------
__global__ __launch_bounds__(256) void k_convW(const float* __restrict__ Wc,
                                               ushort* __restrict__ Wcb){
  int idx = blockIdx.x*256 + threadIdx.x;
  if (idx < 1024*2048) Wcb[idx] = f2bf(Wc[idx]);
}

// ---------------- gather + bf16 convert: XB[n][k] = bf16(embed[x[n]][k]) ----------------
__global__ __launch_bounds__(256) void k_gather(const int* __restrict__ x,
                                                const float* __restrict__ embed,
                                                ushort* __restrict__ XB){
  size_t g = (size_t)blockIdx.x*256 + threadIdx.x;
  const size_t total = (size_t)NT_ * 128;   // 8-element chunks
  for (; g < total; g += (size_t)gridDim.x*256){
    size_t row = g >> 7;
    int cj = (int)(g & 127) * 8;
    int tok = x[row];
    const float* src = embed + (size_t)tok*1024 + cj;
    float4 v0 = *(const float4*)src;
    float4 v1 = *(const float4*)(src + 4);
    uint4 o;
    o.x = (uint)f2bf(v0.x) | ((uint)f2bf(v0.y) << 16);
    o.y = (uint)f2bf(v0.z) | ((uint)f2bf(v0.w) << 16);
    o.z = (uint)f2bf(v1.x) | ((uint)f2bf(v1.y) << 16);
    o.w = (uint)f2bf(v1.z) | ((uint)f2bf(v1.w) << 16);
    *(uint4*)&XB[g*8] = o;
  }
}

// ---------------- big GEMM: A2[t][b][o] = bf16( sum_k XB[n][k]*Wcb[o][k] + bc[o] ), n=b*T+t ----------------
__global__ __launch_bounds__(256) void k_gemmA(const ushort* __restrict__ XB,
                                               const ushort* __restrict__ Wcb,
                                               const float* __restrict__ bc,
                                               ushort* __restrict__ A2){
  __shared__ ushort As[128*64];
  __shared__ ushort Bs[128*64];
  const int bx = blockIdx.x;
  const int nt = bx & 7, mt = bx >> 3;
  const int tid = threadIdx.x, w = tid >> 6, l = tid & 63;
  const int wm = w >> 1, wn = w & 1;
  f32x4 acc[4][4];
  #pragma unroll
  for (int i = 0; i < 4; ++i)
    #pragma unroll
    for (int j = 0; j < 4; ++j) acc[i][j] = (f32x4){0.f,0.f,0.f,0.f};

  const int lrow = l >> 3, lcol = (l & 7) * 8;
  for (int kt = 0; kt < 16; ++kt){
    #pragma unroll
    for (int i = 0; i < 4; ++i){
      int cc = i*4 + w;
      const ushort* ga = XB  + (size_t)(mt*128 + cc*8 + lrow)*1024 + kt*64 + lcol;
      ASYNC_COPY16(ga, (char*)As + cc*1024);
      const ushort* gb = Wcb + (size_t)(nt*128 + cc*8 + lrow)*2048 + kt*64 + lcol;
      ASYNC_COPY16(gb, (char*)Bs + cc*1024);
    }
    __syncthreads();
    #pragma unroll
    for (int ks = 0; ks < 2; ++ks){
      short8 a[4], b[4];
      #pragma unroll
      for (int mi = 0; mi < 4; ++mi)
        a[mi] = *(const short8*)&As[(wm*64 + mi*16 + (l & 15))*64 + ks*32 + (l >> 4)*8];
      #pragma unroll
      for (int ni = 0; ni < 4; ++ni)
        b[ni] = *(const short8*)&Bs[(wn*64 + ni*16 + (l & 15))*64 + ks*32 + (l >> 4)*8];
      #pragma unroll
      for (int mi = 0; mi < 4; ++mi)
        #pragma unroll
        for (int ni = 0; ni < 4; ++ni)
          acc[mi][ni] = __builtin_amdgcn_mfma_f32_16x16x32_bf16(a[mi], b[ni], acc[mi][ni], 0, 0, 0);
    }
    __syncthreads();
  }
  const int col0 = nt*128 + wn*64;
  const int row0 = mt*128 + wm*64;
  #pragma unroll
  for (int ni = 0; ni < 4; ++ni){
    int col = col0 + ni*16 + (l & 15);
    float bias = bc[col];
    #pragma unroll
    for (int mi = 0; mi < 4; ++mi)
      #pragma unroll
      for (int r = 0; r < 4; ++r){
        int row = row0 + mi*16 + (l >> 4)*4 + r;   // n = b*T + t
        int b_i = row >> 9, t_i = row & 511;
        A2[((size_t)t_i*B_ + b_i)*1024 + col] = f2bf(acc[mi][ni][r] + bias);
      }
  }
}

// ---------------- gate x-part: G0/G2[t*B+b] = sum_k XB[n][k]*Wg[j][k] + bg[j], j in {0,2} ----------------
__global__ __launch_bounds__(256) void k_gateG(const ushort* __restrict__ XB,
                                               const float* __restrict__ Wg,
                                               const float* __restrict__ bgv,
                                               float* __restrict__ G0,
                                               float* __restrict__ G2){
  int tid = threadIdx.x, w = tid >> 6, l = tid & 63;
  size_t n = (size_t)blockIdx.x*4 + w;
  const ushort* xr = XB + n*1024;
  int k0 = l * 16;
  float s0 = 0.f, s2 = 0.f;
  #pragma unroll
  for (int h = 0; h < 2; ++h){
    short8 xv = *(const short8*)&xr[k0 + h*8];
    #pragma unroll
    for (int e = 0; e < 8; ++e){
      float xf = bf2f((ushort)xv[e]);
      s0 += xf * Wg[(size_t)0*2048 + k0 + h*8 + e];
      s2 += xf * Wg[(size_t)2*2048 + k0 + h*8 + e];
    }
  }
  for (int off = 32; off; off >>= 1){ s0 += __shfl_xor(s0, off, 64); s2 += __shfl_xor(s2, off, 64); }
  if (l == 0){
    int b_i = (int)(n >> 9), t_i = (int)(n & 511);
    G0[(size_t)t_i*B_ + b_i] = s0 + bgv[0];
    G2[(size_t)t_i*B_ + b_i] = s2 + bgv[2];
  }
}

// ---------------- dual-mode flag barrier, time-bounded ----------------
// fast: plain flag store -> same-XCD L2; sc0 polls; buffer_inv (L1-only) exit.
// slow: agent-scope stores/loads + agent acquire fence (R3-proven path).
// All spins bounded by realtime clock; sticky `bail` + global `dead` guarantee
// forward progress (worst case: fast wrong answer, never a GPU wedge).
static __device__ __forceinline__ void flagbar(uint* flags, uint* dead, int oc, uint target,
                                               bool fast, bool& bail, long long tstart){
  __syncthreads();          // drains each wave's vmcnt: h stores are in cache
  const int tid = threadIdx.x;
  if (!bail){
    if (tid == 0){
      if (fast) ((volatile uint*)flags)[oc*16] = target;
      else      __hip_atomic_store(&flags[oc*16], target, __ATOMIC_RELAXED, __HIP_MEMORY_SCOPE_AGENT);
    }
    if (tid < 64){
      long long t0 = rtclock();
      const uint* myf = &flags[(tid & 31)*16];
      uint it = 0;
      while (true){
        uint v;
        if (tid < 32) v = fast ? poll_sc0(myf)
                               : __hip_atomic_load(myf, __ATOMIC_RELAXED, __HIP_MEMORY_SCOPE_AGENT);
        else v = target;
        if (__all((int)(v >= target))) break;
        if ((++it & 63u) == 0u){
          if (__hip_atomic_load(dead, __ATOMIC_RELAXED, __HIP_MEMORY_SCOPE_AGENT)){ bail = true; break; }
          long long now = rtclock();
          if (now - t0 > 4000000LL || now - tstart > 60000000LL){
            if (tid == 0) __hip_atomic_store(dead, 1u, __ATOMIC_RELAXED, __HIP_MEMORY_SCOPE_AGENT);
            bail = true; break;
          }
        }
        __builtin_amdgcn_s_sleep(1);
      }
      if (fast) asm volatile("buffer_inv\n\ts_waitcnt vmcnt(0)" ::: "memory");
      else      __builtin_amdgcn_fence(__ATOMIC_ACQUIRE, "agent");
    }
  }
  __syncthreads();
}

// ---------------- persistent recurrence ----------------
// 256 WGs: bg = blk&7 (batch-group of 16 rows; XCD-local under round-robin),
// oc = blk>>3 (32 out cols). ~111KB LDS forces 1 WG/CU; grid==256==#CUs => co-resident.
// Startup probe verifies the fast (XCD-local L2) barrier; consensus falls back to
// the R3-proven agent-scope barrier if the probe fails anywhere.
__global__ __launch_bounds__(256, 1) void k_recur(const ushort* __restrict__ Wcb,
                                                  const float*  __restrict__ Wg,
                                                  const ushort* __restrict__ A2,
                                                  const float*  __restrict__ G0,
                                                  const float*  __restrict__ G2,
                                                  const float*  __restrict__ alive,
                                                  ushort* __restrict__ hglob,   // [2][B][1024]
                                                  float*  __restrict__ hsum,    // [B][1024]
                                                  uint*   __restrict__ bar){
  __shared__ ushort WhhS[32*1024];      // 64KB, XOR-swizzled rows (out-cols)
  __shared__ ushort hS[4*16*256];       // 32KB, [wave][row][k-slice], swizzled
  __shared__ ushort wgS[3*1024];        // 6KB: row0=wg0, row1=wg2, row2=zeros (bf16)
  __shared__ float  upart[4][16][33];   // 8448B cross-wave K-partials (odd stride)
  __shared__ float  gpart[4][16][2];    // gate K-partials

  const int blk = blockIdx.x;
  const int bg = blk & 7, oc = blk >> 3;
  const int tid = threadIdx.x, w = tid >> 6, l = tid & 63;
  const long long tstart = rtclock();

  // ---- prologue: Whh slice -> LDS (swizzled write) ----
  #pragma unroll
  for (int it = 0; it < 16; ++it){
    int ch = it*256 + tid;            // 4096 chunks of 16B
    int ci = ch >> 7;                 // local col 0..31
    int kb = (ch & 127) * 16;         // byte in 2048B row
    const char* src = (const char*)Wcb + (((size_t)(oc*32 + ci)*2048 + 1024) * 2) + kb;
    uint4 v = *(const uint4*)src;
    *(uint4*)((char*)WhhS + ci*2048 + (kb ^ ((ci & 7) << 4))) = v;
  }
  #pragma unroll
  for (int it = 0; it < 12; ++it){
    int idx = it*256 + tid;           // 0..3071
    int j = idx >> 10, k = idx & 1023;
    float v = (j == 0) ? Wg[(size_t)0*2048 + 1024 + k]
            : (j == 1) ? Wg[(size_t)2*2048 + 1024 + k] : 0.f;
    wgS[idx] = f2bf(v);
  }
  __syncthreads();

  uint* flags    = bar + bg*512;          // step-barrier flags (32 slots x 64B)
  uint* pflags   = bar + 4096 + bg*512;   // probe/consensus flags
  uint* dead     = bar + 8192;
  uint* modefail = bar + 8193;
  bool bail = false;

  // ---- probe the fast (same-XCD L2) path, time-bounded ----
  {
    bool ok = true;
    if (tid == 0) ((volatile uint*)pflags)[oc*16] = 1u;
    if (tid < 64){
      long long t0 = rtclock();
      const uint* myf = &pflags[(tid & 31)*16];
      while (true){
        uint v = (tid < 32) ? poll_sc0(myf) : 1u;
        if (__all((int)(v >= 1))) break;
        if (rtclock() - t0 > 50000LL){ ok = false; break; }   // ~0.5-2ms
        __builtin_amdgcn_s_sleep(1);
      }
    }
    if (tid == 0 && !ok)
      __hip_atomic_fetch_or(modefail, 1u, __ATOMIC_RELAXED, __HIP_MEMORY_SCOPE_AGENT);
  }
  // ---- consensus via one agent-scope barrier (proven slow path) ----
  flagbar(pflags, dead, oc, 2u, false, bail, tstart);
  const bool fast = (__hip_atomic_load(modefail, __ATOMIC_RELAXED, __HIP_MEMORY_SCOPE_AGENT) == 0u);

  const int r_ep = tid >> 4;                 // epilogue row 0..15
  const int c0   = (tid & 15) * 2;           // epilogue col pair
  const int b_ep = bg*16 + r_ep;
  const int lr   = l & 15, lk = (l >> 4) * 8;
  const int gsel = (lr == 0) ? 0 : (lr == 2 ? 2048 : 4096);   // byte offset into wgS
  float hs0 = 0.f, hs1 = 0.f;

  // prefetch step-0 inputs into registers
  uint  av  = *(const uint*)&A2[((size_t)0*B_ + b_ep)*1024 + oc*32 + c0];
  float gx0 = G0[b_ep], gx2 = G2[b_ep];
  float au  = alive[0];

  for (int t = 0; t < T_; ++t){
    // ---- stage wave-private h K-slice (pre-swizzled global source -> linear LDS) ----
    const ushort* hprev = hglob + (size_t)(t & 1)*B_*H_ + (size_t)bg*16*1024;
    #pragma unroll
    for (int j = 0; j < 8; ++j){
      int r = j*2 + (l >> 5);
      int s = l & 31;
      const ushort* src = hprev + (size_t)r*1024 + w*256 + ((s ^ (r & 7)) * 8);
      ASYNC_COPY16(src, (char*)hS + w*8192 + j*1024);
    }
    asm volatile("s_waitcnt vmcnt(0)" ::: "memory");   // this wave's slice ready

    // ---- u + gates via MFMA (K split across waves) ----
    f32x4 uacc0 = (f32x4){0.f,0.f,0.f,0.f};
    f32x4 uacc1 = (f32x4){0.f,0.f,0.f,0.f};
    f32x4 gacc  = (f32x4){0.f,0.f,0.f,0.f};
    #pragma unroll
    for (int ks = 0; ks < 8; ++ks){
      int kbh  = (ks*32 + lk) * 2;
      int swzh = kbh ^ ((lr & 7) << 4);
      short8 a  = *(const short8*)((const char*)hS + w*8192 + lr*512 + swzh);
      int kbw  = (w*256 + ks*32 + lk) * 2;
      int swzw = kbw ^ ((lr & 7) << 4);
      short8 b0 = *(const short8*)((const char*)WhhS + lr*2048 + swzw);
      short8 b1 = *(const short8*)((const char*)WhhS + (16 + lr)*2048 + swzw);
      short8 gv = *(const short8*)((const char*)wgS + gsel + kbw);
      uacc0 = __builtin_amdgcn_mfma_f32_16x16x32_bf16(a, b0, uacc0, 0, 0, 0);
      uacc1 = __builtin_amdgcn_mfma_f32_16x16x32_bf16(a, b1, uacc1, 0, 0, 0);
      gacc  = __builtin_amdgcn_mfma_f32_16x16x32_bf16(a, gv, gacc,  0, 0, 0);
    }
    #pragma unroll
    for (int r4 = 0; r4 < 4; ++r4){
      int m = (l >> 4)*4 + r4;
      upart[w][m][lr]      = uacc0[r4];
      upart[w][m][16 + lr] = uacc1[r4];
      if (lr == 0) gpart[w][m][0] = gacc[r4];
      if (lr == 2) gpart[w][m][1] = gacc[r4];
    }
    __syncthreads();

    // ---- epilogue: 2 outputs per thread ----
    float u0 = upart[0][r_ep][c0]   + upart[1][r_ep][c0]   + upart[2][r_ep][c0]   + upart[3][r_ep][c0];
    float u1 = upart[0][r_ep][c0+1] + upart[1][r_ep][c0+1] + upart[2][r_ep][c0+1] + upart[3][r_ep][c0+1];
    float gp0 = gpart[0][r_ep][0] + gpart[1][r_ep][0] + gpart[2][r_ep][0] + gpart[3][r_ep][0];
    float gp2 = gpart[0][r_ep][1] + gpart[1][r_ep][1] + gpart[2][r_ep][1] + gpart[3][r_ep][1];
    float gi = fsig(gx0 + gp0);
    float go = fsig(gx2 + gp2);
    float a0 = bf2f((ushort)(av & 0xffffu));
    float a1 = bf2f((ushort)(av >> 16));
    float hn0 = go * ftanh(gi * ftanh(a0 + u0));
    float hn1 = go * ftanh(gi * ftanh(a1 + u1));
    hs0 += au * hn0;
    hs1 += au * hn1;
    uint hv2 = (uint)f2bf(hn0) | ((uint)f2bf(hn1) << 16);
    uint* hdst = (uint*)&hglob[(size_t)((t + 1) & 1)*B_*H_ + (size_t)b_ep*1024 + oc*32 + c0];
    if (fast) *(volatile uint*)hdst = hv2;
    else      __hip_atomic_store(hdst, hv2, __ATOMIC_RELAXED, __HIP_MEMORY_SCOPE_AGENT);

    // ---- prefetch next step's read-only inputs (overlaps the barrier wait) ----
    int tn = (t < T_-1) ? t + 1 : t;
    av  = *(const uint*)&A2[((size_t)tn*B_ + b_ep)*1024 + oc*32 + c0];
    gx0 = G0[(size_t)tn*B_ + b_ep];
    gx2 = G2[(size_t)tn*B_ + b_ep];
    au  = alive[tn];

    // ---- group barrier (skip after final step) ----
    if (t < T_-1) flagbar(flags, dead, oc, (uint)(t + 1), fast, bail, tstart);
  }

  hsum[(size_t)b_ep*1024 + oc*32 + c0]     = hs0;
  hsum[(size_t)b_ep*1024 + oc*32 + c0 + 1] = hs1;
}

// ---------------- output: out[b][c] = dot(hsum[b], Wo[c]) / aliveSum + bo[c] ----------------
__global__ __launch_bounds__(256) void k_out(const float* __restrict__ hsum,
                                             const float* __restrict__ Wo,
                                             const float* __restrict__ bo,
                                             const float* __restrict__ aliveSum,
                                             float* __restrict__ out){
  __shared__ float accs[NC_];
  int b = blockIdx.x, tid = threadIdx.x;
  if (tid < NC_) accs[tid] = 0.f;
  __syncthreads();
  int k0 = tid * 4;
  float4 hv = *(const float4*)&hsum[(size_t)b*1024 + k0];
  float part[NC_];
  #pragma unroll
  for (int c = 0; c < NC_; ++c){
    const float* wr = Wo + (size_t)c*1024 + k0;
    part[c] = hv.x*wr[0] + hv.y*wr[1] + hv.z*wr[2] + hv.w*wr[3];
  }
  #pragma unroll
  for (int c = 0; c < NC_; ++c){
    float v = part[c];
    for (int off = 32; off; off >>= 1) v += __shfl_xor(v, off, 64);
    if ((tid & 63) == 0) atomicAdd(&accs[c], v);
  }
  __syncthreads();
  if (tid < NC_) out[b*NC_ + tid] = accs[tid] / aliveSum[0] + bo[tid];
}

extern "C" void kernel_launch(void* const* d_in, const int* in_sizes, int n_in,
                              void* d_out, int out_size, void* d_ws, size_t ws_size,
                              hipStream_t stream){
  const int*   x     = (const int*)  d_in[0];
  const float* embed = (const float*)d_in[1];
  const float* Wg    = (const float*)d_in[2];
  const float* bg    = (const float*)d_in[3];
  const float* Wc    = (const float*)d_in[4];
  const float* bc    = (const float*)d_in[5];
  const float* Wo    = (const float*)d_in[6];
  const float* bo    = (const float*)d_in[7];
  float* out = (float*)d_out;

  // workspace layout (~274 MB)
  char* p = (char*)d_ws;
  ushort* XB    = (ushort*)p;  p += (size_t)NT_*1024*2;     // 134.2MB
  ushort* A2    = (ushort*)p;  p += (size_t)NT_*1024*2;     // 134.2MB  [t][b][1024]
  ushort* Wcb   = (ushort*)p;  p += (size_t)1024*2048*2;    // 4MB
  float*  G0    = (float*)p;   p += (size_t)NT_*4;          // 256KB
  float*  G2    = (float*)p;   p += (size_t)NT_*4;          // 256KB
  ushort* hglob = (ushort*)p;  p += (size_t)2*B_*H_*2;      // 512KB
  float*  hsum  = (float*)p;   p += (size_t)B_*H_*4;        // 512KB
  float*  alive = (float*)p;   p += (size_t)T_*4;
  float*  aliveSum = (float*)p; p += 256;
  uint*   bar   = (uint*)p;    p += 64*1024;                // flags/probe/dead/modefail

  (void)ws_size; (void)in_sizes; (void)n_in; (void)out_size;

  hipMemsetAsync(hglob, 0, (size_t)B_*H_*2, stream);   // h0 = 0 (buffer slot 0)
  hipMemsetAsync(bar,   0, 64*1024, stream);           // barrier state

  k_alive <<<1,    512, 0, stream>>>(x, alive, aliveSum);
  k_convW <<<8192, 256, 0, stream>>>(Wc, Wcb);
  k_gather<<<4096, 256, 0, stream>>>(x, embed, XB);
  k_gemmA <<<4096, 256, 0, stream>>>(XB, Wcb, bc, A2);
  k_gateG <<<16384,256, 0, stream>>>(XB, Wg, bg, G0, G2);

  k_recur<<<256, 256, 0, stream>>>(Wcb, Wg, A2, G0, G2, alive, hglob, hsum, bar);

  k_out<<<B_, 256, 0, stream>>>(hsum, Wo, bo, aliveSum, out);
}

// Round 6
// 6503.292 us; speedup vs baseline: 6.3753x; 6.3753x over previous
//
#include <hip/hip_runtime.h>
#include <hip/hip_bf16.h>
#include <stdint.h>

#define B_  128
#define T_  512
#define H_  1024
#define E_  1024
#define NC_ 10
#define NT_ (B_*T_)   // 65536

// bar[] layout (uint indices)
#define BAR_CNT   0      // + xcc*16   (8 slots)
#define BAR_DEAD  128
#define BAR_MF    129    // bit0 = rank invalid, bit1 = probe fail
#define BAR_CONS  256    // + blk*16   (256 slots)
#define BAR_PROBE 4608   // + bg*512 + oc*16
#define BAR_STEP  8704   // + bg*512 + oc*16

typedef __attribute__((ext_vector_type(8))) short  short8;
typedef __attribute__((ext_vector_type(4))) float  f32x4;

static __device__ __forceinline__ float bf2f(ushort u){
  union { uint u; float f; } v; v.u = ((uint)u) << 16; return v.f;
}
static __device__ __forceinline__ ushort f2bf(float f){
  union { float f; uint u; } v; v.f = f;
  uint u = v.u;
  uint lsb = (u >> 16) & 1u;
  u += 0x7fffu + lsb;          // round-to-nearest-even
  return (ushort)(u >> 16);
}
static __device__ __forceinline__ float fsig(float x){ return 1.f / (1.f + __expf(-x)); }
static __device__ __forceinline__ float ftanh(float x){
  float e = __expf(2.f * x);
  return 1.f - 2.f / (e + 1.f);
}

// async global->LDS, 16B per lane. LDS dst wave-uniform; HW adds lane*16. Global src per-lane.
#define ASYNC_COPY16(gsrc, ldsdst) \
  __builtin_amdgcn_global_load_lds((const __attribute__((address_space(1))) uint32_t*)(gsrc), \
                                   (__attribute__((address_space(3))) uint32_t*)(ldsdst), 16, 0, 0)

// L2-coherent poll load: sc0 bypasses L1, reads this XCD's L2.
static __device__ __forceinline__ uint poll_sc0(const uint* p){
  uint v;
  asm volatile("global_load_dword %0, %1, off sc0\n\t"
               "s_waitcnt vmcnt(0)"
               : "=v"(v) : "v"(p) : "memory");
  return v;
}
static __device__ __forceinline__ long long rtclock(){
  return (long long)__builtin_amdgcn_s_memrealtime();
}

// ---------------- alive[t] = cumprod(colsum(x) != 0) ----------------
__global__ __launch_bounds__(512) void k_alive(const int* __restrict__ x,
                                               float* __restrict__ alive,
                                               float* __restrict__ aliveSum){
  __shared__ float fl[T_];
  int t = threadIdx.x;
  int s = 0;
  for (int b = 0; b < B_; ++b) s += x[b*T_ + t];
  fl[t] = (s != 0) ? 1.f : 0.f;
  __syncthreads();
  if (t == 0){
    float run = 1.f, sum = 0.f;
    for (int i = 0; i < T_; ++i){ run *= fl[i]; alive[i] = run; sum += run; }
    aliveSum[0] = sum;
  }
}

// ---------------- weight conversion: Wc -> bf16 (stride 2048) ----------------
__global__ __launch_bounds__(256) void k_convW(const float* __restrict__ Wc,
                                               ushort* __restrict__ Wcb){
  int idx = blockIdx.x*256 + threadIdx.x;
  if (idx < 1024*2048) Wcb[idx] = f2bf(Wc[idx]);
}

// ---------------- gather + bf16 convert: XB[n][k] = bf16(embed[x[n]][k]) ----------------
__global__ __launch_bounds__(256) void k_gather(const int* __restrict__ x,
                                                const float* __restrict__ embed,
                                                ushort* __restrict__ XB){
  size_t g = (size_t)blockIdx.x*256 + threadIdx.x;
  const size_t total = (size_t)NT_ * 128;   // 8-element chunks
  for (; g < total; g += (size_t)gridDim.x*256){
    size_t row = g >> 7;
    int cj = (int)(g & 127) * 8;
    int tok = x[row];
    const float* src = embed + (size_t)tok*1024 + cj;
    float4 v0 = *(const float4*)src;
    float4 v1 = *(const float4*)(src + 4);
    uint4 o;
    o.x = (uint)f2bf(v0.x) | ((uint)f2bf(v0.y) << 16);
    o.y = (uint)f2bf(v0.z) | ((uint)f2bf(v0.w) << 16);
    o.z = (uint)f2bf(v1.x) | ((uint)f2bf(v1.y) << 16);
    o.w = (uint)f2bf(v1.z) | ((uint)f2bf(v1.w) << 16);
    *(uint4*)&XB[g*8] = o;
  }
}

// ---------------- big GEMM: A2[t][b][o] = bf16( sum_k XB[n][k]*Wcb[o][k] + bc[o] ), n=b*T+t ----------------
__global__ __launch_bounds__(256) void k_gemmA(const ushort* __restrict__ XB,
                                               const ushort* __restrict__ Wcb,
                                               const float* __restrict__ bc,
                                               ushort* __restrict__ A2){
  __shared__ ushort As[128*64];
  __shared__ ushort Bs[128*64];
  const int bx = blockIdx.x;
  const int nt = bx & 7, mt = bx >> 3;
  const int tid = threadIdx.x, w = tid >> 6, l = tid & 63;
  const int wm = w >> 1, wn = w & 1;
  f32x4 acc[4][4];
  #pragma unroll
  for (int i = 0; i < 4; ++i)
    #pragma unroll
    for (int j = 0; j < 4; ++j) acc[i][j] = (f32x4){0.f,0.f,0.f,0.f};

  const int lrow = l >> 3, lcol = (l & 7) * 8;
  for (int kt = 0; kt < 16; ++kt){
    #pragma unroll
    for (int i = 0; i < 4; ++i){
      int cc = i*4 + w;
      const ushort* ga = XB  + (size_t)(mt*128 + cc*8 + lrow)*1024 + kt*64 + lcol;
      ASYNC_COPY16(ga, (char*)As + cc*1024);
      const ushort* gb = Wcb + (size_t)(nt*128 + cc*8 + lrow)*2048 + kt*64 + lcol;
      ASYNC_COPY16(gb, (char*)Bs + cc*1024);
    }
    __syncthreads();
    #pragma unroll
    for (int ks = 0; ks < 2; ++ks){
      short8 a[4], b[4];
      #pragma unroll
      for (int mi = 0; mi < 4; ++mi)
        a[mi] = *(const short8*)&As[(wm*64 + mi*16 + (l & 15))*64 + ks*32 + (l >> 4)*8];
      #pragma unroll
      for (int ni = 0; ni < 4; ++ni)
        b[ni] = *(const short8*)&Bs[(wn*64 + ni*16 + (l & 15))*64 + ks*32 + (l >> 4)*8];
      #pragma unroll
      for (int mi = 0; mi < 4; ++mi)
        #pragma unroll
        for (int ni = 0; ni < 4; ++ni)
          acc[mi][ni] = __builtin_amdgcn_mfma_f32_16x16x32_bf16(a[mi], b[ni], acc[mi][ni], 0, 0, 0);
    }
    __syncthreads();
  }
  const int col0 = nt*128 + wn*64;
  const int row0 = mt*128 + wm*64;
  #pragma unroll
  for (int ni = 0; ni < 4; ++ni){
    int col = col0 + ni*16 + (l & 15);
    float bias = bc[col];
    #pragma unroll
    for (int mi = 0; mi < 4; ++mi)
      #pragma unroll
      for (int r = 0; r < 4; ++r){
        int row = row0 + mi*16 + (l >> 4)*4 + r;   // n = b*T + t
        int b_i = row >> 9, t_i = row & 511;
        A2[((size_t)t_i*B_ + b_i)*1024 + col] = f2bf(acc[mi][ni][r] + bias);
      }
  }
}

// ---------------- gate x-part: G0/G2[t*B+b] = sum_k XB[n][k]*Wg[j][k] + bg[j], j in {0,2} ----------------
__global__ __launch_bounds__(256) void k_gateG(const ushort* __restrict__ XB,
                                               const float* __restrict__ Wg,
                                               const float* __restrict__ bgv,
                                               float* __restrict__ G0,
                                               float* __restrict__ G2){
  int tid = threadIdx.x, w = tid >> 6, l = tid & 63;
  size_t n = (size_t)blockIdx.x*4 + w;
  const ushort* xr = XB + n*1024;
  int k0 = l * 16;
  float s0 = 0.f, s2 = 0.f;
  #pragma unroll
  for (int h = 0; h < 2; ++h){
    short8 xv = *(const short8*)&xr[k0 + h*8];
    #pragma unroll
    for (int e = 0; e < 8; ++e){
      float xf = bf2f((ushort)xv[e]);
      s0 += xf * Wg[(size_t)0*2048 + k0 + h*8 + e];
      s2 += xf * Wg[(size_t)2*2048 + k0 + h*8 + e];
    }
  }
  for (int off = 32; off; off >>= 1){ s0 += __shfl_xor(s0, off, 64); s2 += __shfl_xor(s2, off, 64); }
  if (l == 0){
    int b_i = (int)(n >> 9), t_i = (int)(n & 511);
    G0[(size_t)t_i*B_ + b_i] = s0 + bgv[0];
    G2[(size_t)t_i*B_ + b_i] = s2 + bgv[2];
  }
}

// ---------------- probe barrier (fast semantics), returns ok (valid in wave 0) ----------------
static __device__ __forceinline__ bool gprobe(uint* pf, int oc, uint target, long long budget){
  bool ok = true;
  __syncthreads();
  if (threadIdx.x == 0) ((volatile uint*)pf)[oc*16] = target;
  if (threadIdx.x < 64){
    long long t0 = rtclock();
    const uint* myf = &pf[(threadIdx.x & 31)*16];
    while (true){
      uint v = (threadIdx.x < 32) ? poll_sc0(myf) : target;
      if (__all((int)(v >= target))) break;
      if (rtclock() - t0 > budget){ ok = false; break; }
      __builtin_amdgcn_s_sleep(1);
    }
    asm volatile("buffer_inv" ::: "memory");
  }
  __syncthreads();
  return ok;
}

// ---------------- dual-mode step barrier, time-bounded ----------------
static __device__ __forceinline__ void flagbar(uint* flags, uint* dead, int oc, uint target,
                                               bool fast, bool& bail, long long tstart){
  __syncthreads();          // drains vmcnt: this WG's h stores committed
  const int tid = threadIdx.x;
  if (!bail){
    if (tid == 0){
      if (fast) ((volatile uint*)flags)[oc*16] = target;
      else      __hip_atomic_store(&flags[oc*16], target, __ATOMIC_RELAXED, __HIP_MEMORY_SCOPE_AGENT);
    }
    if (tid < 64){
      long long t0 = rtclock();
      const uint* myf = &flags[(tid & 31)*16];
      uint it = 0;
      while (true){
        uint v;
        if (tid < 32) v = fast ? poll_sc0(myf)
                               : __hip_atomic_load(myf, __ATOMIC_RELAXED, __HIP_MEMORY_SCOPE_AGENT);
        else v = target;
        if (__all((int)(v >= target))) break;
        if ((++it & 63u) == 0u){
          if (__hip_atomic_load(dead, __ATOMIC_RELAXED, __HIP_MEMORY_SCOPE_AGENT)){ bail = true; break; }
          long long now = rtclock();
          if (now - t0 > 4000000LL || now - tstart > 1000000000LL){
            if (tid == 0) __hip_atomic_store(dead, 1u, __ATOMIC_RELAXED, __HIP_MEMORY_SCOPE_AGENT);
            bail = true; break;
          }
        }
        __builtin_amdgcn_s_sleep(1);
      }
      if (fast) asm volatile("buffer_inv\n\ts_waitcnt vmcnt(0)" ::: "memory");
      else      __builtin_amdgcn_fence(__ATOMIC_ACQUIRE, "agent");
    }
  }
  __syncthreads();
}

// ---------------- persistent recurrence ----------------
// 256 WGs. XCD topology is MEASURED at start (HW_REG_XCC_ID + rank): group bg = xcc
// (32 WGs, all on one XCD, sharing its L2), oc = rank (32-col slice). Probe verifies
// the fast intra-L2 barrier with a latency gate; consensus falls back to the R3-proven
// agent-scope barrier + blk-based mapping. ~111KB LDS forces 1 WG/CU -> co-resident.
__global__ __launch_bounds__(256, 1) void k_recur(const ushort* __restrict__ Wcb,
                                                  const float*  __restrict__ Wg,
                                                  const ushort* __restrict__ A2,
                                                  const float*  __restrict__ G0,
                                                  const float*  __restrict__ G2,
                                                  const float*  __restrict__ alive,
                                                  ushort* __restrict__ hglob,   // [2][B][1024]
                                                  float*  __restrict__ hsum,    // [B][1024]
                                                  uint*   __restrict__ bar){
  __shared__ ushort WhhS[32*1024];      // 64KB, XOR-swizzled rows (out-cols)
  __shared__ ushort hS[4*16*256];       // 32KB, [wave][row][k-slice], swizzled
  __shared__ ushort wgS[3*1032];        // 6.2KB: padded rows (bank-phase 0/4/8)
  __shared__ float  upart[4][16][33];   // 8448B cross-wave K-partials (odd stride)
  __shared__ float  gpart[4][16][2];    // gate K-partials
  __shared__ int    smap[2];

  const int blk = blockIdx.x;
  const int tid = threadIdx.x, w = tid >> 6, l = tid & 63;
  const long long tstart = rtclock();

  uint* dead = &bar[BAR_DEAD];
  bool bail = false;

  // ---- phase 0: measure XCD topology ----
  if (tid == 0){
    uint xcc;
    asm volatile("s_getreg_b32 %0, hwreg(HW_REG_XCC_ID)" : "=s"(xcc));
    xcc &= 7u;
    uint rank = __hip_atomic_fetch_add(&bar[BAR_CNT + xcc*16], 1u,
                                       __ATOMIC_RELAXED, __HIP_MEMORY_SCOPE_AGENT);
    smap[0] = (int)xcc; smap[1] = (int)(rank & 31u);
    if (rank >= 32u)
      __hip_atomic_fetch_or(&bar[BAR_MF], 1u, __ATOMIC_RELAXED, __HIP_MEMORY_SCOPE_AGENT);
  }
  __syncthreads();
  const int mbg = smap[0], moc = smap[1];

  // ---- phase 1: probe the fast path (2 warm-ups + 1 latency-gated) ----
  {
    uint* pf = &bar[BAR_PROBE + mbg*512];
    bool ok = gprobe(pf, moc, 1u, 200000LL);     // absorb dispatch skew
    ok &= gprobe(pf, moc, 2u, 200000LL);
    ok &= gprobe(pf, moc, 3u, 600LL);            // steady-state gate ~6us
    if (tid == 0 && !ok)
      __hip_atomic_fetch_or(&bar[BAR_MF], 2u, __ATOMIC_RELAXED, __HIP_MEMORY_SCOPE_AGENT);
  }

  // ---- phase 2: all-256 consensus (agent scope) ----
  {
    if (tid == 0)
      __hip_atomic_store(&bar[BAR_CONS + blk*16], 1u, __ATOMIC_RELEASE, __HIP_MEMORY_SCOPE_AGENT);
    if (tid < 64){
      long long t0 = rtclock();
      while (true){
        bool done = true;
        #pragma unroll
        for (int j = 0; j < 4; ++j){
          uint v = __hip_atomic_load(&bar[BAR_CONS + (tid + j*64)*16],
                                     __ATOMIC_RELAXED, __HIP_MEMORY_SCOPE_AGENT);
          done &= (v >= 1u);
        }
        if (__all((int)done)) break;
        if (rtclock() - t0 > 4000000LL){
          if (tid == 0) __hip_atomic_store(dead, 1u, __ATOMIC_RELAXED, __HIP_MEMORY_SCOPE_AGENT);
          bail = true; break;
        }
        __builtin_amdgcn_s_sleep(2);
      }
      __builtin_amdgcn_fence(__ATOMIC_ACQUIRE, "agent");
    }
    __syncthreads();
  }
  const uint mf = __hip_atomic_load(&bar[BAR_MF], __ATOMIC_RELAXED, __HIP_MEMORY_SCOPE_AGENT);
  const bool measured = !(mf & 1u);
  const bool fast = (mf == 0u);
  const int bg = measured ? mbg : (blk & 7);
  const int oc = measured ? moc : (blk >> 3);

  // ---- prologue: Whh slice -> LDS (swizzled write) ----
  #pragma unroll
  for (int it = 0; it < 16; ++it){
    int ch = it*256 + tid;            // 4096 chunks of 16B
    int ci = ch >> 7;                 // local col 0..31
    int kb = (ch & 127) * 16;         // byte in 2048B row
    const char* src = (const char*)Wcb + (((size_t)(oc*32 + ci)*2048 + 1024) * 2) + kb;
    uint4 v = *(const uint4*)src;
    *(uint4*)((char*)WhhS + ci*2048 + (kb ^ ((ci & 7) << 4))) = v;
  }
  for (int it = 0; it < 13; ++it){
    int idx = it*256 + tid;           // 0..3095
    if (idx < 3096){
      int j = idx / 1032, k = idx - j*1032;
      float v = 0.f;
      if (k < 1024){
        if (j == 0)      v = Wg[(size_t)0*2048 + 1024 + k];
        else if (j == 1) v = Wg[(size_t)2*2048 + 1024 + k];
      }
      wgS[idx] = f2bf(v);
    }
  }
  __syncthreads();

  const int r_ep = tid >> 4;                 // epilogue row 0..15
  const int c0   = (tid & 15) * 2;           // epilogue col pair
  const int b_ep = bg*16 + r_ep;
  const int lr   = l & 15, lk = (l >> 4) * 8;
  const int gsel = (lr == 0) ? 0 : (lr == 2 ? 2064 : 4128);   // byte offset into wgS (padded rows)
  float hs0 = 0.f, hs1 = 0.f;

  uint* flags = &bar[BAR_STEP + bg*512];

  // prefetch step-0 inputs into registers
  uint  av  = *(const uint*)&A2[((size_t)0*B_ + b_ep)*1024 + oc*32 + c0];
  float gx0 = G0[b_ep], gx2 = G2[b_ep];
  float au  = alive[0];

  for (int t = 0; t < T_; ++t){
    // ---- stage wave-private h K-slice (pre-swizzled global source -> linear LDS) ----
    const ushort* hprev = hglob + (size_t)(t & 1)*B_*H_ + (size_t)bg*16*1024;
    #pragma unroll
    for (int j = 0; j < 8; ++j){
      int r = j*2 + (l >> 5);
      int s = l & 31;
      const ushort* src = hprev + (size_t)r*1024 + w*256 + ((s ^ (r & 7)) * 8);
      ASYNC_COPY16(src, (char*)hS + w*8192 + j*1024);
    }
    asm volatile("s_waitcnt vmcnt(0)" ::: "memory");   // this wave's slice ready

    // ---- u + gates via MFMA (K split across waves) ----
    f32x4 uacc0 = (f32x4){0.f,0.f,0.f,0.f};
    f32x4 uacc1 = (f32x4){0.f,0.f,0.f,0.f};
    f32x4 gacc  = (f32x4){0.f,0.f,0.f,0.f};
    #pragma unroll
    for (int ks = 0; ks < 8; ++ks){
      int kbh  = (ks*32 + lk) * 2;
      int swzh = kbh ^ ((lr & 7) << 4);
      short8 a  = *(const short8*)((const char*)hS + w*8192 + lr*512 + swzh);
      int kbw  = (w*256 + ks*32 + lk) * 2;
      int swzw = kbw ^ ((lr & 7) << 4);
      short8 b0 = *(const short8*)((const char*)WhhS + lr*2048 + swzw);
      short8 b1 = *(const short8*)((const char*)WhhS + (16 + lr)*2048 + swzw);
      short8 gv = *(const short8*)((const char*)wgS + gsel + kbw);
      uacc0 = __builtin_amdgcn_mfma_f32_16x16x32_bf16(a, b0, uacc0, 0, 0, 0);
      uacc1 = __builtin_amdgcn_mfma_f32_16x16x32_bf16(a, b1, uacc1, 0, 0, 0);
      gacc  = __builtin_amdgcn_mfma_f32_16x16x32_bf16(a, gv, gacc,  0, 0, 0);
    }
    #pragma unroll
    for (int r4 = 0; r4 < 4; ++r4){
      int m = (l >> 4)*4 + r4;
      upart[w][m][lr]      = uacc0[r4];
      upart[w][m][16 + lr] = uacc1[r4];
      if (lr == 0) gpart[w][m][0] = gacc[r4];
      if (lr == 2) gpart[w][m][1] = gacc[r4];
    }
    __syncthreads();

    // ---- epilogue: 2 outputs per thread ----
    float u0 = upart[0][r_ep][c0]   + upart[1][r_ep][c0]   + upart[2][r_ep][c0]   + upart[3][r_ep][c0];
    float u1 = upart[0][r_ep][c0+1] + upart[1][r_ep][c0+1] + upart[2][r_ep][c0+1] + upart[3][r_ep][c0+1];
    float gp0 = gpart[0][r_ep][0] + gpart[1][r_ep][0] + gpart[2][r_ep][0] + gpart[3][r_ep][0];
    float gp2 = gpart[0][r_ep][1] + gpart[1][r_ep][1] + gpart[2][r_ep][1] + gpart[3][r_ep][1];
    float gi = fsig(gx0 + gp0);
    float go = fsig(gx2 + gp2);
    float a0 = bf2f((ushort)(av & 0xffffu));
    float a1 = bf2f((ushort)(av >> 16));
    float hn0 = go * ftanh(gi * ftanh(a0 + u0));
    float hn1 = go * ftanh(gi * ftanh(a1 + u1));
    hs0 += au * hn0;
    hs1 += au * hn1;
    uint hv2 = (uint)f2bf(hn0) | ((uint)f2bf(hn1) << 16);
    uint* hdst = (uint*)&hglob[(size_t)((t + 1) & 1)*B_*H_ + (size_t)b_ep*1024 + oc*32 + c0];
    if (fast) *(volatile uint*)hdst = hv2;
    else      __hip_atomic_store(hdst, hv2, __ATOMIC_RELAXED, __HIP_MEMORY_SCOPE_AGENT);

    // ---- prefetch next step's read-only inputs (overlaps the barrier wait) ----
    int tn = (t < T_-1) ? t + 1 : t;
    av  = *(const uint*)&A2[((size_t)tn*B_ + b_ep)*1024 + oc*32 + c0];
    gx0 = G0[(size_t)tn*B_ + b_ep];
    gx2 = G2[(size_t)tn*B_ + b_ep];
    au  = alive[tn];

    // ---- group barrier (skip after final step) ----
    if (t < T_-1) flagbar(flags, dead, oc, (uint)(t + 1), fast, bail, tstart);
  }

  hsum[(size_t)b_ep*1024 + oc*32 + c0]     = hs0;
  hsum[(size_t)b_ep*1024 + oc*32 + c0 + 1] = hs1;
}

// ---------------- output: out[b][c] = dot(hsum[b], Wo[c]) / aliveSum + bo[c] ----------------
__global__ __launch_bounds__(256) void k_out(const float* __restrict__ hsum,
                                             const float* __restrict__ Wo,
                                             const float* __restrict__ bo,
                                             const float* __restrict__ aliveSum,
                                             float* __restrict__ out){
  __shared__ float accs[NC_];
  int b = blockIdx.x, tid = threadIdx.x;
  if (tid < NC_) accs[tid] = 0.f;
  __syncthreads();
  int k0 = tid * 4;
  float4 hv = *(const float4*)&hsum[(size_t)b*1024 + k0];
  float part[NC_];
  #pragma unroll
  for (int c = 0; c < NC_; ++c){
    const float* wr = Wo + (size_t)c*1024 + k0;
    part[c] = hv.x*wr[0] + hv.y*wr[1] + hv.z*wr[2] + hv.w*wr[3];
  }
  #pragma unroll
  for (int c = 0; c < NC_; ++c){
    float v = part[c];
    for (int off = 32; off; off >>= 1) v += __shfl_xor(v, off, 64);
    if ((tid & 63) == 0) atomicAdd(&accs[c], v);
  }
  __syncthreads();
  if (tid < NC_) out[b*NC_ + tid] = accs[tid] / aliveSum[0] + bo[tid];
}

extern "C" void kernel_launch(void* const* d_in, const int* in_sizes, int n_in,
                              void* d_out, int out_size, void* d_ws, size_t ws_size,
                              hipStream_t stream){
  const int*   x     = (const int*)  d_in[0];
  const float* embed = (const float*)d_in[1];
  const float* Wg    = (const float*)d_in[2];
  const float* bg    = (const float*)d_in[3];
  const float* Wc    = (const float*)d_in[4];
  const float* bc    = (const float*)d_in[5];
  const float* Wo    = (const float*)d_in[6];
  const float* bo    = (const float*)d_in[7];
  float* out = (float*)d_out;

  // workspace layout (~274 MB)
  char* p = (char*)d_ws;
  ushort* XB    = (ushort*)p;  p += (size_t)NT_*1024*2;     // 134.2MB
  ushort* A2    = (ushort*)p;  p += (size_t)NT_*1024*2;     // 134.2MB  [t][b][1024]
  ushort* Wcb   = (ushort*)p;  p += (size_t)1024*2048*2;    // 4MB
  float*  G0    = (float*)p;   p += (size_t)NT_*4;          // 256KB
  float*  G2    = (float*)p;   p += (size_t)NT_*4;          // 256KB
  ushort* hglob = (ushort*)p;  p += (size_t)2*B_*H_*2;      // 512KB
  float*  hsum  = (float*)p;   p += (size_t)B_*H_*4;        // 512KB
  float*  alive = (float*)p;   p += (size_t)T_*4;
  float*  aliveSum = (float*)p; p += 256;
  uint*   bar   = (uint*)p;    p += 64*1024;                // topology/probe/consensus/step flags

  (void)ws_size; (void)in_sizes; (void)n_in; (void)out_size;

  hipMemsetAsync(hglob, 0, (size_t)B_*H_*2, stream);   // h0 = 0 (buffer slot 0)
  hipMemsetAsync(bar,   0, 64*1024, stream);           // barrier state

  k_alive <<<1,    512, 0, stream>>>(x, alive, aliveSum);
  k_convW <<<8192, 256, 0, stream>>>(Wc, Wcb);
  k_gather<<<4096, 256, 0, stream>>>(x, embed, XB);
  k_gemmA <<<4096, 256, 0, stream>>>(XB, Wcb, bc, A2);
  k_gateG <<<16384,256, 0, stream>>>(XB, Wg, bg, G0, G2);

  k_recur<<<256, 256, 0, stream>>>(Wcb, Wg, A2, G0, G2, alive, hglob, hsum, bar);

  k_out<<<B_, 256, 0, stream>>>(hsum, Wo, bo, aliveSum, out);
}

// Round 7
// 1751.667 us; speedup vs baseline: 23.6690x; 3.7126x over previous
//
#include <hip/hip_runtime.h>
#include <hip/hip_bf16.h>
#include <stdint.h>

#define B_  128
#define T_  512
#define H_  1024
#define E_  1024
#define NC_ 10
#define NT_ (B_*T_)   // 65536

// bar[] layout (uint indices): step flags [8 groups][32 slots x 16], then dead
#define BAR_STEP  0
#define BAR_DEAD  4096

typedef __attribute__((ext_vector_type(8))) short  short8;
typedef __attribute__((ext_vector_type(4))) float  f32x4;

static __device__ __forceinline__ float bf2f(ushort u){
  union { uint u; float f; } v; v.u = ((uint)u) << 16; return v.f;
}
static __device__ __forceinline__ ushort f2bf(float f){
  union { float f; uint u; } v; v.f = f;
  uint u = v.u;
  uint lsb = (u >> 16) & 1u;
  u += 0x7fffu + lsb;          // round-to-nearest-even
  return (ushort)(u >> 16);
}
static __device__ __forceinline__ float fsig(float x){ return 1.f / (1.f + __expf(-x)); }
static __device__ __forceinline__ float ftanh(float x){
  float e = __expf(2.f * x);
  return 1.f - 2.f / (e + 1.f);
}

// async global->LDS, 16B per lane. LDS dst wave-uniform; HW adds lane*16. Global src per-lane.
#define ASYNC_COPY16(gsrc, ldsdst) \
  __builtin_amdgcn_global_load_lds((const __attribute__((address_space(1))) uint32_t*)(gsrc), \
                                   (__attribute__((address_space(3))) uint32_t*)(ldsdst), 16, 0, 0)

static __device__ __forceinline__ long long rtclock(){
  return (long long)__builtin_amdgcn_s_memrealtime();
}

// ---------------- alive[t] = cumprod(colsum(x) != 0) ----------------
__global__ __launch_bounds__(512) void k_alive(const int* __restrict__ x,
                                               float* __restrict__ alive,
                                               float* __restrict__ aliveSum){
  __shared__ float fl[T_];
  int t = threadIdx.x;
  int s = 0;
  for (int b = 0; b < B_; ++b) s += x[b*T_ + t];
  fl[t] = (s != 0) ? 1.f : 0.f;
  __syncthreads();
  if (t == 0){
    float run = 1.f, sum = 0.f;
    for (int i = 0; i < T_; ++i){ run *= fl[i]; alive[i] = run; sum += run; }
    aliveSum[0] = sum;
  }
}

// ---------------- weight conversion: Wc -> bf16 (stride 2048) ----------------
__global__ __launch_bounds__(256) void k_convW(const float* __restrict__ Wc,
                                               ushort* __restrict__ Wcb){
  int idx = blockIdx.x*256 + threadIdx.x;
  if (idx < 1024*2048) Wcb[idx] = f2bf(Wc[idx]);
}

// ---------------- gather + bf16 convert: XB[n][k] = bf16(embed[x[n]][k]) ----------------
__global__ __launch_bounds__(256) void k_gather(const int* __restrict__ x,
                                                const float* __restrict__ embed,
                                                ushort* __restrict__ XB){
  size_t g = (size_t)blockIdx.x*256 + threadIdx.x;
  const size_t total = (size_t)NT_ * 128;   // 8-element chunks
  for (; g < total; g += (size_t)gridDim.x*256){
    size_t row = g >> 7;
    int cj = (int)(g & 127) * 8;
    int tok = x[row];
    const float* src = embed + (size_t)tok*1024 + cj;
    float4 v0 = *(const float4*)src;
    float4 v1 = *(const float4*)(src + 4);
    uint4 o;
    o.x = (uint)f2bf(v0.x) | ((uint)f2bf(v0.y) << 16);
    o.y = (uint)f2bf(v0.z) | ((uint)f2bf(v0.w) << 16);
    o.z = (uint)f2bf(v1.x) | ((uint)f2bf(v1.y) << 16);
    o.w = (uint)f2bf(v1.z) | ((uint)f2bf(v1.w) << 16);
    *(uint4*)&XB[g*8] = o;
  }
}

// ---------------- big GEMM: A2[t][b][o] = bf16( sum_k XB[n][k]*Wcb[o][k] + bc[o] ), n=b*T+t ----------------
__global__ __launch_bounds__(256) void k_gemmA(const ushort* __restrict__ XB,
                                               const ushort* __restrict__ Wcb,
                                               const float* __restrict__ bc,
                                               ushort* __restrict__ A2){
  __shared__ ushort As[128*64];
  __shared__ ushort Bs[128*64];
  const int bx = blockIdx.x;
  const int nt = bx & 7, mt = bx >> 3;
  const int tid = threadIdx.x, w = tid >> 6, l = tid & 63;
  const int wm = w >> 1, wn = w & 1;
  f32x4 acc[4][4];
  #pragma unroll
  for (int i = 0; i < 4; ++i)
    #pragma unroll
    for (int j = 0; j < 4; ++j) acc[i][j] = (f32x4){0.f,0.f,0.f,0.f};

  const int lrow = l >> 3, lcol = (l & 7) * 8;
  for (int kt = 0; kt < 16; ++kt){
    #pragma unroll
    for (int i = 0; i < 4; ++i){
      int cc = i*4 + w;
      const ushort* ga = XB  + (size_t)(mt*128 + cc*8 + lrow)*1024 + kt*64 + lcol;
      ASYNC_COPY16(ga, (char*)As + cc*1024);
      const ushort* gb = Wcb + (size_t)(nt*128 + cc*8 + lrow)*2048 + kt*64 + lcol;
      ASYNC_COPY16(gb, (char*)Bs + cc*1024);
    }
    __syncthreads();
    #pragma unroll
    for (int ks = 0; ks < 2; ++ks){
      short8 a[4], b[4];
      #pragma unroll
      for (int mi = 0; mi < 4; ++mi)
        a[mi] = *(const short8*)&As[(wm*64 + mi*16 + (l & 15))*64 + ks*32 + (l >> 4)*8];
      #pragma unroll
      for (int ni = 0; ni < 4; ++ni)
        b[ni] = *(const short8*)&Bs[(wn*64 + ni*16 + (l & 15))*64 + ks*32 + (l >> 4)*8];
      #pragma unroll
      for (int mi = 0; mi < 4; ++mi)
        #pragma unroll
        for (int ni = 0; ni < 4; ++ni)
          acc[mi][ni] = __builtin_amdgcn_mfma_f32_16x16x32_bf16(a[mi], b[ni], acc[mi][ni], 0, 0, 0);
    }
    __syncthreads();
  }
  const int col0 = nt*128 + wn*64;
  const int row0 = mt*128 + wm*64;
  #pragma unroll
  for (int ni = 0; ni < 4; ++ni){
    int col = col0 + ni*16 + (l & 15);
    float bias = bc[col];
    #pragma unroll
    for (int mi = 0; mi < 4; ++mi)
      #pragma unroll
      for (int r = 0; r < 4; ++r){
        int row = row0 + mi*16 + (l >> 4)*4 + r;   // n = b*T + t
        int b_i = row >> 9, t_i = row & 511;
        A2[((size_t)t_i*B_ + b_i)*1024 + col] = f2bf(acc[mi][ni][r] + bias);
      }
  }
}

// ---------------- gate x-part: G0/G2[t*B+b] = sum_k XB[n][k]*Wg[j][k] + bg[j], j in {0,2} ----------------
__global__ __launch_bounds__(256) void k_gateG(const ushort* __restrict__ XB,
                                               const float* __restrict__ Wg,
                                               const float* __restrict__ bgv,
                                               float* __restrict__ G0,
                                               float* __restrict__ G2){
  int tid = threadIdx.x, w = tid >> 6, l = tid & 63;
  size_t n = (size_t)blockIdx.x*4 + w;
  const ushort* xr = XB + n*1024;
  int k0 = l * 16;
  float s0 = 0.f, s2 = 0.f;
  #pragma unroll
  for (int h = 0; h < 2; ++h){
    short8 xv = *(const short8*)&xr[k0 + h*8];
    #pragma unroll
    for (int e = 0; e < 8; ++e){
      float xf = bf2f((ushort)xv[e]);
      s0 += xf * Wg[(size_t)0*2048 + k0 + h*8 + e];
      s2 += xf * Wg[(size_t)2*2048 + k0 + h*8 + e];
    }
  }
  for (int off = 32; off; off >>= 1){ s0 += __shfl_xor(s0, off, 64); s2 += __shfl_xor(s2, off, 64); }
  if (l == 0){
    int b_i = (int)(n >> 9), t_i = (int)(n & 511);
    G0[(size_t)t_i*B_ + b_i] = s0 + bgv[0];
    G2[(size_t)t_i*B_ + b_i] = s2 + bgv[2];
  }
}

// ---------------- persistent recurrence, fence-free IF exchange ----------------
// 256 WGs: bg = blk&7 (batch-group of 16 rows), oc = blk>>3 (32 out cols).
// ~111KB LDS forces 1 WG/CU; grid==256==#CUs => co-resident (plain launch).
// Whh slice + gate weights LDS-resident for all 512 steps. h and flags go through
// the coherence point (IF): stores = agent atomics (R3-proven write-through);
// flag polls = agent atomic loads (R3-proven); h slab reads = explicit sc1 loads
// (bypass L1+L2). NO acquire fence in the loop -> L2 stays warm for A2 stream.
// Per-wave poll fan-in is 8 (wave w needs producers oc in [8w, 8w+8)).
__global__ __launch_bounds__(256, 1) void k_recur(const ushort* __restrict__ Wcb,
                                                  const float*  __restrict__ Wg,
                                                  const ushort* __restrict__ A2,
                                                  const float*  __restrict__ G0,
                                                  const float*  __restrict__ G2,
                                                  const float*  __restrict__ alive,
                                                  ushort* __restrict__ hglob,   // [2][B][1024]
                                                  float*  __restrict__ hsum,    // [B][1024]
                                                  uint*   __restrict__ bar){
  __shared__ ushort WhhS[32*1024];      // 64KB, XOR-swizzled rows (out-cols)
  __shared__ ushort hS[4*16*256];       // 32KB, [wave][row][k-slice], swizzled
  __shared__ ushort wgS[3*1032];        // 6.2KB: padded rows (wg0, wg2, zeros)
  __shared__ float  upart[4][16][33];   // 8448B cross-wave K-partials (odd stride)
  __shared__ float  gpart[4][16][2];    // gate K-partials

  const int blk = blockIdx.x;
  const int bg = blk & 7, oc = blk >> 3;
  const int tid = threadIdx.x, w = tid >> 6, l = tid & 63;
  const long long tstart = rtclock();

  // ---- prologue: Whh slice -> LDS (swizzled write) ----
  #pragma unroll
  for (int it = 0; it < 16; ++it){
    int ch = it*256 + tid;            // 4096 chunks of 16B
    int ci = ch >> 7;                 // local col 0..31
    int kb = (ch & 127) * 16;         // byte in 2048B row
    const char* src = (const char*)Wcb + (((size_t)(oc*32 + ci)*2048 + 1024) * 2) + kb;
    uint4 v = *(const uint4*)src;
    *(uint4*)((char*)WhhS + ci*2048 + (kb ^ ((ci & 7) << 4))) = v;
  }
  for (int it = 0; it < 13; ++it){
    int idx = it*256 + tid;           // 0..3095
    if (idx < 3096){
      int j = idx / 1032, k = idx - j*1032;
      float v = 0.f;
      if (k < 1024){
        if (j == 0)      v = Wg[(size_t)0*2048 + 1024 + k];
        else if (j == 1) v = Wg[(size_t)2*2048 + 1024 + k];
      }
      wgS[idx] = f2bf(v);
    }
  }
  __syncthreads();

  const int r_ep = tid >> 4;                 // epilogue row 0..15
  const int c0   = (tid & 15) * 2;           // epilogue col pair
  const int b_ep = bg*16 + r_ep;
  const int lr   = l & 15, lk = (l >> 4) * 8;
  const int gsel = (lr == 0) ? 0 : (lr == 2 ? 2064 : 4128);   // byte offset into wgS (padded rows)
  float hs0 = 0.f, hs1 = 0.f;

  uint* flags = &bar[BAR_STEP + bg*512];
  uint* dead  = &bar[BAR_DEAD];
  const uint* myflag = &flags[((w << 3) | (l & 7)) * 16];  // this wave's 8 producers
  bool bail = false;

  // prefetch step-0 inputs into registers
  uint  av  = *(const uint*)&A2[((size_t)0*B_ + b_ep)*1024 + oc*32 + c0];
  float gx0 = G0[b_ep], gx2 = G2[b_ep];
  float au  = alive[0];

  for (int t = 0; t < T_; ++t){
    // ---- wait: this wave's 8 producers finished step t-1 (per-wave, no fence) ----
    if (t > 0 && !bail){
      const uint tgt = (uint)t;
      long long t0 = rtclock();
      uint it = 0;
      while (true){
        uint v = tgt;
        if (l < 8) v = __hip_atomic_load(myflag, __ATOMIC_RELAXED, __HIP_MEMORY_SCOPE_AGENT);
        if (__all((int)(v >= tgt))) break;
        if ((++it & 63u) == 0u){
          if (__hip_atomic_load(dead, __ATOMIC_RELAXED, __HIP_MEMORY_SCOPE_AGENT)){ bail = true; break; }
          long long now = rtclock();
          if (now - t0 > 4000000LL || now - tstart > 1000000000LL){
            if (l == 0) __hip_atomic_store(dead, 1u, __ATOMIC_RELAXED, __HIP_MEMORY_SCOPE_AGENT);
            bail = true; break;
          }
        }
        __builtin_amdgcn_s_sleep(1);
      }
    }

    // ---- stage wave-private h K-slice: sc1 loads (coherence point) -> regs -> LDS ----
    const ushort* hprev = hglob + (size_t)(t & 1)*B_*H_ + (size_t)bg*16*1024;
    uint4 hv[8];
    #pragma unroll
    for (int j = 0; j < 8; ++j){
      int r = j*2 + (l >> 5);
      int s = l & 31;
      const void* src = hprev + (size_t)r*1024 + w*256 + ((s ^ (r & 7)) * 8);
      asm volatile("global_load_dwordx4 %0, %1, off sc1" : "=v"(hv[j]) : "v"(src));
    }
    asm volatile("s_waitcnt vmcnt(0)" ::: "memory");
    __builtin_amdgcn_sched_barrier(0);
    #pragma unroll
    for (int j = 0; j < 8; ++j)
      *(uint4*)((char*)hS + w*8192 + j*1024 + (size_t)l*16) = hv[j];

    // ---- u + gates via MFMA (K split across waves) ----
    f32x4 uacc0 = (f32x4){0.f,0.f,0.f,0.f};
    f32x4 uacc1 = (f32x4){0.f,0.f,0.f,0.f};
    f32x4 gacc  = (f32x4){0.f,0.f,0.f,0.f};
    #pragma unroll
    for (int ks = 0; ks < 8; ++ks){
      int kbh  = (ks*32 + lk) * 2;
      int swzh = kbh ^ ((lr & 7) << 4);
      short8 a  = *(const short8*)((const char*)hS + w*8192 + lr*512 + swzh);
      int kbw  = (w*256 + ks*32 + lk) * 2;
      int swzw = kbw ^ ((lr & 7) << 4);
      short8 b0 = *(const short8*)((const char*)WhhS + lr*2048 + swzw);
      short8 b1 = *(const short8*)((const char*)WhhS + (16 + lr)*2048 + swzw);
      short8 gv = *(const short8*)((const char*)wgS + gsel + kbw);
      uacc0 = __builtin_amdgcn_mfma_f32_16x16x32_bf16(a, b0, uacc0, 0, 0, 0);
      uacc1 = __builtin_amdgcn_mfma_f32_16x16x32_bf16(a, b1, uacc1, 0, 0, 0);
      gacc  = __builtin_amdgcn_mfma_f32_16x16x32_bf16(a, gv, gacc,  0, 0, 0);
    }
    #pragma unroll
    for (int r4 = 0; r4 < 4; ++r4){
      int m = (l >> 4)*4 + r4;
      upart[w][m][lr]      = uacc0[r4];
      upart[w][m][16 + lr] = uacc1[r4];
      if (lr == 0) gpart[w][m][0] = gacc[r4];
      if (lr == 2) gpart[w][m][1] = gacc[r4];
    }
    __syncthreads();

    // ---- epilogue: 2 outputs per thread ----
    float u0 = upart[0][r_ep][c0]   + upart[1][r_ep][c0]   + upart[2][r_ep][c0]   + upart[3][r_ep][c0];
    float u1 = upart[0][r_ep][c0+1] + upart[1][r_ep][c0+1] + upart[2][r_ep][c0+1] + upart[3][r_ep][c0+1];
    float gp0 = gpart[0][r_ep][0] + gpart[1][r_ep][0] + gpart[2][r_ep][0] + gpart[3][r_ep][0];
    float gp2 = gpart[0][r_ep][1] + gpart[1][r_ep][1] + gpart[2][r_ep][1] + gpart[3][r_ep][1];
    float gi = fsig(gx0 + gp0);
    float go = fsig(gx2 + gp2);
    float a0 = bf2f((ushort)(av & 0xffffu));
    float a1 = bf2f((ushort)(av >> 16));
    float hn0 = go * ftanh(gi * ftanh(a0 + u0));
    float hn1 = go * ftanh(gi * ftanh(a1 + u1));
    hs0 += au * hn0;
    hs1 += au * hn1;
    // write-through h store to the coherence point (R3-proven)
    uint hv2 = (uint)f2bf(hn0) | ((uint)f2bf(hn1) << 16);
    uint* hdst = (uint*)&hglob[(size_t)((t + 1) & 1)*B_*H_ + (size_t)b_ep*1024 + oc*32 + c0];
    __hip_atomic_store(hdst, hv2, __ATOMIC_RELAXED, __HIP_MEMORY_SCOPE_AGENT);

    // ---- prefetch next step's read-only inputs (overlaps the store drain) ----
    int tn = (t < T_-1) ? t + 1 : t;
    av  = *(const uint*)&A2[((size_t)tn*B_ + b_ep)*1024 + oc*32 + c0];
    gx0 = G0[(size_t)tn*B_ + b_ep];
    gx2 = G2[(size_t)tn*B_ + b_ep];
    au  = alive[tn];

    // ---- signal: all waves' h stores drained by the barrier's vmcnt(0) ----
    __syncthreads();
    if (tid == 0 && t < T_-1)
      __hip_atomic_store(&flags[oc*16], (uint)(t + 1), __ATOMIC_RELAXED, __HIP_MEMORY_SCOPE_AGENT);
  }

  hsum[(size_t)b_ep*1024 + oc*32 + c0]     = hs0;
  hsum[(size_t)b_ep*1024 + oc*32 + c0 + 1] = hs1;
}

// ---------------- output: out[b][c] = dot(hsum[b], Wo[c]) / aliveSum + bo[c] ----------------
__global__ __launch_bounds__(256) void k_out(const float* __restrict__ hsum,
                                             const float* __restrict__ Wo,
                                             const float* __restrict__ bo,
                                             const float* __restrict__ aliveSum,
                                             float* __restrict__ out){
  __shared__ float accs[NC_];
  int b = blockIdx.x, tid = threadIdx.x;
  if (tid < NC_) accs[tid] = 0.f;
  __syncthreads();
  int k0 = tid * 4;
  float4 hv = *(const float4*)&hsum[(size_t)b*1024 + k0];
  float part[NC_];
  #pragma unroll
  for (int c = 0; c < NC_; ++c){
    const float* wr = Wo + (size_t)c*1024 + k0;
    part[c] = hv.x*wr[0] + hv.y*wr[1] + hv.z*wr[2] + hv.w*wr[3];
  }
  #pragma unroll
  for (int c = 0; c < NC_; ++c){
    float v = part[c];
    for (int off = 32; off; off >>= 1) v += __shfl_xor(v, off, 64);
    if ((tid & 63) == 0) atomicAdd(&accs[c], v);
  }
  __syncthreads();
  if (tid < NC_) out[b*NC_ + tid] = accs[tid] / aliveSum[0] + bo[tid];
}

extern "C" void kernel_launch(void* const* d_in, const int* in_sizes, int n_in,
                              void* d_out, int out_size, void* d_ws, size_t ws_size,
                              hipStream_t stream){
  const int*   x     = (const int*)  d_in[0];
  const float* embed = (const float*)d_in[1];
  const float* Wg    = (const float*)d_in[2];
  const float* bg    = (const float*)d_in[3];
  const float* Wc    = (const float*)d_in[4];
  const float* bc    = (const float*)d_in[5];
  const float* Wo    = (const float*)d_in[6];
  const float* bo    = (const float*)d_in[7];
  float* out = (float*)d_out;

  // workspace layout (~274 MB)
  char* p = (char*)d_ws;
  ushort* XB    = (ushort*)p;  p += (size_t)NT_*1024*2;     // 134.2MB
  ushort* A2    = (ushort*)p;  p += (size_t)NT_*1024*2;     // 134.2MB  [t][b][1024]
  ushort* Wcb   = (ushort*)p;  p += (size_t)1024*2048*2;    // 4MB
  float*  G0    = (float*)p;   p += (size_t)NT_*4;          // 256KB
  float*  G2    = (float*)p;   p += (size_t)NT_*4;          // 256KB
  ushort* hglob = (ushort*)p;  p += (size_t)2*B_*H_*2;      // 512KB
  float*  hsum  = (float*)p;   p += (size_t)B_*H_*4;        // 512KB
  float*  alive = (float*)p;   p += (size_t)T_*4;
  float*  aliveSum = (float*)p; p += 256;
  uint*   bar   = (uint*)p;    p += 64*1024;                // step flags + dead

  (void)ws_size; (void)in_sizes; (void)n_in; (void)out_size;

  hipMemsetAsync(hglob, 0, (size_t)B_*H_*2, stream);   // h0 = 0 (buffer slot 0)
  hipMemsetAsync(bar,   0, 64*1024, stream);           // barrier state

  k_alive <<<1,    512, 0, stream>>>(x, alive, aliveSum);
  k_convW <<<8192, 256, 0, stream>>>(Wc, Wcb);
  k_gather<<<4096, 256, 0, stream>>>(x, embed, XB);
  k_gemmA <<<4096, 256, 0, stream>>>(XB, Wcb, bc, A2);
  k_gateG <<<16384,256, 0, stream>>>(XB, Wg, bg, G0, G2);

  k_recur<<<256, 256, 0, stream>>>(Wcb, Wg, A2, G0, G2, alive, hglob, hsum, bar);

  k_out<<<B_, 256, 0, stream>>>(hsum, Wo, bo, aliveSum, out);
}